// Round 11
// baseline (352.606 us; speedup 1.0000x reference)
//
#include <hip/hip_runtime.h>
#include <hip/hip_bf16.h>

typedef __hip_bfloat16 bf16;
typedef __attribute__((ext_vector_type(8))) short short8;
typedef __attribute__((ext_vector_type(4))) float floatx4;

#define MF(a, b, c) __builtin_amdgcn_mfma_f32_16x16x32_bf16(a, b, c, 0, 0, 0)
#define ADJ_SLOTS 128

__device__ __forceinline__ float b2f(bf16 v) { return __bfloat162float(v); }
__device__ __forceinline__ unsigned short f2us(float f) {
    bf16 h = __float2bfloat16(f);
    return *(unsigned short*)&h;
}
__device__ __forceinline__ float lo2f(unsigned hv) { return __uint_as_float(hv << 16); }
__device__ __forceinline__ float hi2f(unsigned hv) { return __uint_as_float(hv & 0xffff0000u); }
__device__ __forceinline__ float leaky(float v) { return v > 0.f ? v : 0.2f * v; }

__device__ __forceinline__ float ldw(const void* p, size_t i, int f32) {
    return f32 ? ((const float*)p)[i] : b2f(((const bf16*)p)[i]);
}

template <int F32>
__device__ __forceinline__ float LDWt(const void* p, size_t i) {
    return F32 ? ((const float*)p)[i] : b2f(((const bf16*)p)[i]);
}

// reduce part[0..3] over the 16 lanes of a quad-group (masks 1,2,4,8)
__device__ __forceinline__ void quadred(float part[4]) {
#pragma unroll
    for (int m = 1; m <= 8; m <<= 1)
#pragma unroll
        for (int r = 0; r < 4; r++) part[r] += __shfl_xor(part[r], m);
}

// ---------------- K1: dtype detect + workspace zero + node0/rootb/flag2 ------
// (R7 lesson: no cooperative grid.sync — kernel boundaries are the barrier.)
__global__ void k_detect_zero(const void* x, int* flagd, char* zbase, size_t zbytes,
                              const int* __restrict__ batch, int* __restrict__ node0,
                              unsigned char* __restrict__ rootb,
                              unsigned char* __restrict__ flag2, int N, int zBlocks) {
    int b = blockIdx.x;
    int t = threadIdx.x;
    if (b == 0) {
        __shared__ int sbad;
        if (t == 0) sbad = 0;
        __syncthreads();
        const bf16* xb = (const bf16*)x;
        int bad = 0;
#pragma unroll
        for (int j = 0; j < 16; j++) {
            float v = b2f(xb[t * 16 + j]);  // sample elements 0..4095
            if (!(fabsf(v) < 1e10f)) bad = 1;
        }
        if (bad) sbad = 1;  // benign same-value race
        __syncthreads();
        if (t == 0) flagd[0] = sbad;
    } else if (b < 1 + zBlocks) {
        size_t off = (size_t)(b - 1) * 4096 + (size_t)t * 16;
        if (off < zbytes) *(uint4*)(zbase + off) = make_uint4(0u, 0u, 0u, 0u);
    } else {
        int i = (b - 1 - zBlocks) * 256 + t;
        if (i < N) {
            int bb = batch[i];
            int isroot = (i == 0) || (batch[i - 1] != bb);
            rootb[i] = (unsigned char)isroot;  // dense init: no pre-zero needed
            flag2[i] = (unsigned char)isroot;
            if (isroot) node0[bb] = i;
        }
    }
}

// ---------------- K2: prep — mark2 edge scan, Wt transpose, head-W1
// transposes, small weights, x->bf16 (f32 path; direct-indexed — R9 lesson:
// grid-stride starved the 78 MB convert) ----------------
__global__ void k_prep(const void* __restrict__ x, unsigned short* __restrict__ Ab,
                       int nvec,
                       const void* __restrict__ gw, unsigned short* __restrict__ Wt,
                       const void* as_, const void* ad_, const void* b_,
                       float* asF, float* adF, float* bF,
                       const void* sW_, const void* pW1_, const void* cW1_,
                       const void* fW1_, const void* bW1_, const void* zW1_,
                       unsigned short* __restrict__ Whd,
                       const int* __restrict__ ei, const unsigned char* __restrict__ rootb,
                       unsigned char* __restrict__ flag2, int E,
                       const int* __restrict__ flagd, int nbE) {
    int b = blockIdx.x;
    int t = threadIdx.x;
    if (b < nbE) {
        // mark2: src feeds a graph root -> layer-2 frontier (only SETS bits)
        int e = b * 256 + t;
        if (e < E && rootb[ei[E + e]]) flag2[ei[e]] = 1;
        return;
    }
    int f32 = *flagd;
    b -= nbE;
    if (b < 192) {
        int i = b * 256 + t;  // exactly 3*16384
        int l = i >> 14, rem = i & 16383, n = rem >> 7, k = rem & 127;
        Wt[i] = f2us(ldw(gw, (size_t)l * 16384 + (size_t)k * 128 + n, f32));
    } else if (b < 194) {
        int i = (b - 192) * 256 + t;
        if (i < 384) {
            asF[i] = ldw(as_, i, f32);
            adF[i] = ldw(ad_, i, f32);
            bF[i] = ldw(b_, i, f32);
        }
    } else if (b < 194 + 184) {
        // transposed head W1s -> Whd (bf16, col-major [n][k], zero-padded K)
        // layout: sWt[64][160] @0; pW1t 3x[64][64] @10240; cW1t @22528;
        //         fW1t 2x @26624; bW1t[64][96] @34816; zW1t[64][96] @40960.
        int i = (b - 194) * 256 + t;  // 0..47103
        float v;
        if (i < 10240) {
            int n = i / 160, k = i - n * 160;
            v = (k < 150) ? ldw(sW_, (size_t)k * 64 + n, f32) : 0.f;
        } else if (i < 22528) {
            int j = i - 10240;
            int kk = j >> 12, r = j & 4095, n = r >> 6, k = r & 63;
            v = ldw(pW1_, (size_t)kk * 4096 + (size_t)k * 64 + n, f32);
        } else if (i < 26624) {
            int j = i - 22528;
            int n = j >> 6, k = j & 63;
            v = ldw(cW1_, (size_t)k * 64 + n, f32);
        } else if (i < 34816) {
            int j = i - 26624;
            int kk = j >> 12, r = j & 4095, n = r >> 6, k = r & 63;
            v = ldw(fW1_, (size_t)kk * 4096 + (size_t)k * 64 + n, f32);
        } else if (i < 40960) {
            int j = i - 34816;
            int n = j / 96, k = j - n * 96;
            v = (k < 93) ? ldw(bW1_, (size_t)k * 64 + n, f32) : 0.f;
        } else {
            int j = i - 40960;
            int n = j / 96, k = j - n * 96;
            v = (k < 94) ? ldw(zW1_, (size_t)k * 64 + n, f32) : 0.f;
        }
        Whd[i] = f2us(v);
    } else {
        // x -> bf16 conversion (f32 storage path); one uint4 per thread
        if (!f32) return;
        int i = (b - 194 - 184) * 256 + t;
        if (i < nvec) {
            float4 a = ((const float4*)x)[2 * i];
            float4 c = ((const float4*)x)[2 * i + 1];
            uint4 o;
            o.x = ((unsigned)f2us(a.y) << 16) | f2us(a.x);
            o.y = ((unsigned)f2us(a.w) << 16) | f2us(a.z);
            o.z = ((unsigned)f2us(c.y) << 16) | f2us(c.x);
            o.w = ((unsigned)f2us(c.w) << 16) | f2us(c.z);
            ((uint4*)Ab)[i] = o;
        }
    }
}

// ---------------- K4: cursor scatter + ATOMIC-APPEND worklists ----------------
// No scan kernel: adj offsets are implicit (node*ADJ_SLOTS) and worklists are
// built by per-wave-coalesced atomic append (order nondeterministic; results
// bit-identical — per-node work is independent of worklist position).
// nactp[0] = |wl1| ; nactp[32] = |wl2| (128B apart to avoid line contention).
__global__ void k_scatter_wl(const int* __restrict__ ei,
                             int* __restrict__ cur,
                             const unsigned char* __restrict__ flag1,
                             const unsigned char* __restrict__ flag2,
                             int* __restrict__ adj,
                             int* __restrict__ ovfD, int* __restrict__ ovfS,
                             int* __restrict__ ovfCnt,
                             int* __restrict__ wl1, int* __restrict__ wl2,
                             int* __restrict__ nactp,
                             int E, int N, int eBlocks) {
    int b = blockIdx.x;
    if (b < eBlocks) {
        int e = b * 256 + threadIdx.x;
        if (e >= E) return;
        int d = ei[E + e];
        if (!flag1[d]) return;
        int slot = atomicAdd(&cur[d], 1);
        if (slot < ADJ_SLOTS) {
            adj[(size_t)d * ADJ_SLOTS + slot] = ei[e];
        } else {
            int o = atomicAdd(ovfCnt, 1);
            if (o < E) { ovfD[o] = d; ovfS[o] = ei[e]; }
        }
    } else {
        int i = (b - eBlocks) * 256 + threadIdx.x;
        if (i < N) {
            if (flag1[i]) wl1[atomicAdd(&nactp[0], 1)] = i;
            if (flag2[i]) wl2[atomicAdd(&nactp[32], 1)] = i;
        }
    }
}

// ---------------- MFMA GEMM body: LDS-staged Wt, grid-stride over tiles ------
__device__ __forceinline__ void gemm_body(
    const unsigned short* __restrict__ Asrc, const unsigned short* __restrict__ Wt,
    unsigned short* __restrict__ Bb, float4* __restrict__ asadv,
    const float* __restrict__ asF, const float* __restrict__ adF, int N,
    const int* __restrict__ wl, const int* __restrict__ nactp,
    int bb0, int bstride) {
    __shared__ __align__(16) unsigned short Ws[128 * 136];
    __shared__ __align__(16) unsigned short Cs[64 * 136];

    int t = threadIdx.x;
    int nact = wl ? *nactp : N;
    if (bb0 * 64 >= nact) return;  // idle block: exit before staging

    {
        const uint4* src = (const uint4*)Wt;  // 2048 uint4
#pragma unroll
        for (int k = 0; k < 8; k++) {
            int j = t + k * 256;
            int row = j >> 4, c16 = j & 15;
            *(uint4*)&Ws[row * 136 + c16 * 8] = src[j];
        }
    }
    __syncthreads();

    int lane = t & 63;
    int w = t >> 6;
    int ln = lane & 15;
    int quad = lane >> 4;

    for (int bb = bb0; bb * 64 < nact; bb += bstride) {
        int r0 = bb * 64;
        int idx = r0 + w * 16 + ln;
        bool valid = idx < nact;
        int arow = idx < N ? idx : N - 1;
        if (wl) arow = valid ? wl[idx] : 0;
        bool wave_active = __any((int)valid);

        if (wave_active) {
            const unsigned short* ap = Asrc + (size_t)arow * 128 + quad * 8;

            short8 afrag[4];
            if (valid) {
#pragma unroll
                for (int kt = 0; kt < 4; kt++)
                    afrag[kt] = *(const short8*)(ap + kt * 32);
            } else {
#pragma unroll
                for (int kt = 0; kt < 4; kt++)
                    afrag[kt] = (short8){0, 0, 0, 0, 0, 0, 0, 0};
            }

            floatx4 acc[8];
#pragma unroll
            for (int nt = 0; nt < 8; nt++) acc[nt] = (floatx4){0.f, 0.f, 0.f, 0.f};

#pragma unroll
            for (int nt = 0; nt < 8; nt++) {
                const unsigned short* wp = Ws + (nt * 16 + ln) * 136 + quad * 8;
#pragma unroll
                for (int kt = 0; kt < 4; kt++) {
                    short8 bfrag = *(const short8*)(wp + kt * 32);
                    acc[nt] = MF(afrag[kt], bfrag, acc[nt]);
                }
            }

            float as0[4] = {0, 0, 0, 0}, as1[4] = {0, 0, 0, 0};
            float ad0[4] = {0, 0, 0, 0}, ad1[4] = {0, 0, 0, 0};
#pragma unroll
            for (int nt = 0; nt < 8; nt++) {
                float asc = asF[nt * 16 + ln];
                float adc = adF[nt * 16 + ln];
#pragma unroll
                for (int r = 0; r < 4; r++) {
                    float v = acc[nt][r];
                    Cs[(w * 16 + quad * 4 + r) * 136 + nt * 16 + ln] = f2us(v);
                    if (nt < 4) { as0[r] += v * asc; ad0[r] += v * adc; }
                    else        { as1[r] += v * asc; ad1[r] += v * adc; }
                }
            }
#pragma unroll
            for (int mask = 1; mask <= 8; mask <<= 1) {
#pragma unroll
                for (int r = 0; r < 4; r++) {
                    as0[r] += __shfl_xor(as0[r], mask);
                    as1[r] += __shfl_xor(as1[r], mask);
                    ad0[r] += __shfl_xor(ad0[r], mask);
                    ad1[r] += __shfl_xor(ad1[r], mask);
                }
            }
            if (ln == 0) {
#pragma unroll
                for (int r = 0; r < 4; r++) {
                    int idx3 = r0 + w * 16 + quad * 4 + r;
                    if (idx3 < nact) {
                        int row = wl ? wl[idx3] : idx3;
                        asadv[row] = make_float4(as0[r], as1[r], ad0[r], ad1[r]);
                    }
                }
            }
        }
        __syncthreads();

        {
            int idx2 = r0 + (t >> 2);
            int cseg = (t & 3) * 32;
            if (idx2 < nact) {
                int grow = wl ? wl[idx2] : idx2;
                const short8* srcp = (const short8*)&Cs[(t >> 2) * 136 + cseg];
                short8* dstp = (short8*)&Bb[(size_t)grow * 128 + cseg];
#pragma unroll
                for (int u = 0; u < 4; u++) dstp[u] = srcp[u];
            }
        }
        __syncthreads();  // Cs consumed before next tile overwrites it
    }
}

__global__ __launch_bounds__(256) void k_gemm_mfma(
    const unsigned short* __restrict__ Ab, const unsigned short* __restrict__ Wt,
    unsigned short* __restrict__ Bb, float4* __restrict__ asadv,
    const float* __restrict__ asF, const float* __restrict__ adF, int N,
    const int* __restrict__ wl, const int* __restrict__ nactp) {
    gemm_body(Ab, Wt, Bb, asadv, asF, adF, N, wl, nactp, blockIdx.x, gridDim.x);
}

// K3: layer-0 GEMM (reads x directly when bf16) fused with mark1
__global__ __launch_bounds__(256) void k_gemm0_mark(
    const unsigned short* __restrict__ Ab, const void* __restrict__ xraw,
    const unsigned short* __restrict__ Wt,
    unsigned short* __restrict__ Bb, float4* __restrict__ asadv,
    const float* __restrict__ asF, const float* __restrict__ adF, int N,
    const int* __restrict__ ei, const unsigned char* __restrict__ flag2,
    unsigned char* __restrict__ flag1, int E, int markE, int markN,
    const int* __restrict__ flagd) {
    int b = blockIdx.x;
    if (b < markE) {
        int e = b * 256 + threadIdx.x;
        if (e < E && flag2[ei[E + e]]) flag1[ei[e]] = 1;
        return;
    }
    if (b < markE + markN) {
        int i = (b - markE) * 256 + threadIdx.x;
        if (i < N && flag2[i]) flag1[i] = 1;
        return;
    }
    const unsigned short* Asrc = *flagd ? Ab : (const unsigned short*)xraw;
    gemm_body(Asrc, Wt, Bb, asadv, asF, adF, N, nullptr, nullptr,
              b - markE - markN, gridDim.x - markE - markN);
}

// ---------------- GAT aggregation: grid-stride waves over a worklist ---------
__global__ void k_gat_agg(const uint2* __restrict__ Bu2, const float4* __restrict__ asadv,
                          const int* __restrict__ cur, const int* __restrict__ adj,
                          const int* __restrict__ ovfD, const int* __restrict__ ovfS,
                          const int* __restrict__ ovfCnt,
                          const float* __restrict__ biasF,
                          uint2* __restrict__ Au2,
                          const int* __restrict__ nactp, int dorelu,
                          const int* __restrict__ wl) {
    int totWaves = (gridDim.x * blockDim.x) >> 6;
    int wave0 = (blockIdx.x * blockDim.x + threadIdx.x) >> 6;
    int lane = threadIdx.x & 63;
    int hl = lane & 31;          // lane within node-half
    int hb = lane & 32;          // shfl broadcast base for this half
    int half = lane >> 5;
    int head = hl >> 4;
    int n = *nactp;

    for (int wv = wave0; wv * 2 < n; wv += totWaves) {
        int idx = wv * 2 + half;
        if (idx >= n) continue;  // half-wave masked; shfls stay in-half
        int node = wl[idx];

        float4 self = asadv[node];
        float ad0 = self.z, ad1 = self.w;
        float es0 = __expf(leaky(self.x + ad0));
        float es1 = __expf(leaky(self.y + ad1));

        const int* ap = adj + (size_t)node * ADJ_SLOTS;
        int c = cur[node];
        uint2 hvs = Bu2[(size_t)node * 32 + hl];
        float acc0, acc1, acc2, acc3;

        if (c <= 32) {
            // ---- fast path ----
            int src_r = 0;
            float p0 = 0.f, p1 = 0.f;
            if (hl < c) {
                src_r = ap[hl];
                float4 av = asadv[src_r];
                p0 = __expf(leaky(av.x + ad0));
                p1 = __expf(leaky(av.y + ad1));
            }
            float t0 = p0, t1 = p1;
#pragma unroll
            for (int mask = 1; mask <= 16; mask <<= 1) {
                t0 += __shfl_xor(t0, mask);
                t1 += __shfl_xor(t1, mask);
            }
            float inv0 = 1.f / (es0 + t0 + 1e-16f);
            float inv1 = 1.f / (es1 + t1 + 1e-16f);
            p0 *= inv0;
            p1 *= inv1;
            float aself = head ? es1 * inv1 : es0 * inv0;
            acc0 = aself * lo2f(hvs.x);
            acc1 = aself * hi2f(hvs.x);
            acc2 = aself * lo2f(hvs.y);
            acc3 = aself * hi2f(hvs.y);

            uint2 hq[4];
#pragma unroll
            for (int j = 0; j < 4; j++) {
                int s2 = __shfl(src_r, hb + j);
                hq[j] = make_uint2(0u, 0u);
                if (j < c) hq[j] = Bu2[(size_t)s2 * 32 + hl];
            }

            for (int base = 0; base < c; base += 4) {
                uint2 cu[4];
                float av4[4];
#pragma unroll
                for (int j = 0; j < 4; j++) {
                    cu[j] = hq[j];
                    int idx2 = (base + j) & 31;
                    float a0 = __shfl(p0, hb + idx2);   // full-exec broadcasts
                    float a1 = __shfl(p1, hb + idx2);
                    float a = head ? a1 : a0;
                    av4[j] = (base + j < c) ? a : 0.f;
                }
#pragma unroll
                for (int j = 0; j < 4; j++) {
                    int nx = base + 4 + j;
                    int s2 = __shfl(src_r, hb + (nx & 31));
                    if (nx < c) hq[j] = Bu2[(size_t)s2 * 32 + hl];
                }
#pragma unroll
                for (int j = 0; j < 4; j++) {
                    acc0 += av4[j] * lo2f(cu[j].x);
                    acc1 += av4[j] * hi2f(cu[j].x);
                    acc2 += av4[j] * lo2f(cu[j].y);
                    acc3 += av4[j] * hi2f(cu[j].y);
                }
            }
        } else {
            // ---- slow path (rare, c>32): recompute alphas, no staging ----
            float sum0 = es0, sum1 = es1;
            int cc = min(c, ADJ_SLOTS);
            for (int base = 0; base < cc; base += 32) {
                int i = base + hl;
                float p0 = 0.f, p1 = 0.f;
                if (i < cc) {
                    int s = ap[i];
                    float4 av = asadv[s];
                    p0 = __expf(leaky(av.x + ad0));
                    p1 = __expf(leaky(av.y + ad1));
                }
                float t0 = p0, t1 = p1;
#pragma unroll
                for (int mask = 1; mask <= 16; mask <<= 1) {
                    t0 += __shfl_xor(t0, mask);
                    t1 += __shfl_xor(t1, mask);
                }
                sum0 += t0; sum1 += t1;
            }
            int no = (c > ADJ_SLOTS) ? *ovfCnt : 0;
            for (int oe = 0; oe < no; oe++) {
                if (ovfD[oe] == node) {
                    float4 av = asadv[ovfS[oe]];
                    sum0 += __expf(leaky(av.x + ad0));
                    sum1 += __expf(leaky(av.y + ad1));
                }
            }
            float inv0 = 1.f / (sum0 + 1e-16f);
            float inv1 = 1.f / (sum1 + 1e-16f);
            float aself = head ? es1 * inv1 : es0 * inv0;
            float invh = head ? inv1 : inv0;
            acc0 = aself * lo2f(hvs.x);
            acc1 = aself * hi2f(hvs.x);
            acc2 = aself * lo2f(hvs.y);
            acc3 = aself * hi2f(hvs.y);
            for (int i = 0; i < cc; i++) {
                int s = ap[i];
                float4 av = asadv[s];
                float a = (head ? __expf(leaky(av.y + ad1)) : __expf(leaky(av.x + ad0))) * invh;
                uint2 hv = Bu2[(size_t)s * 32 + hl];
                acc0 += a * lo2f(hv.x);
                acc1 += a * hi2f(hv.x);
                acc2 += a * lo2f(hv.y);
                acc3 += a * hi2f(hv.y);
            }
            for (int oe = 0; oe < no; oe++) {
                if (ovfD[oe] == node) {
                    int s = ovfS[oe];
                    float4 av = asadv[s];
                    float a = (head ? __expf(leaky(av.y + ad1)) : __expf(leaky(av.x + ad0))) * invh;
                    uint2 hv = Bu2[(size_t)s * 32 + hl];
                    acc0 += a * lo2f(hv.x);
                    acc1 += a * hi2f(hv.x);
                    acc2 += a * lo2f(hv.y);
                    acc3 += a * hi2f(hv.y);
                }
            }
        }

        float4 bb4 = ((const float4*)biasF)[hl];
        float q0 = acc0 + bb4.x;
        float q1 = acc1 + bb4.y;
        float q2 = acc2 + bb4.z;
        float q3 = acc3 + bb4.w;
        if (dorelu) {
            q0 = fmaxf(q0, 0.f); q1 = fmaxf(q1, 0.f);
            q2 = fmaxf(q2, 0.f); q3 = fmaxf(q3, 0.f);
        }
        Au2[(size_t)node * 32 + hl] =
            make_uint2(((unsigned)f2us(q1) << 16) | f2us(q0),
                       ((unsigned)f2us(q3) << 16) | f2us(q2));
    }
}

// ---------------- heads: fused root aggregation + MFMA-batched MLP chain -----
// Prologue: each wave runs the proven 2-node-per-wave aggregation for its 16
// graphs (8 pair-iterations), writing results straight into the hinS LDS tile
// (no hroot global round-trip, no separate launch).
template <int F32>
__device__ void heads_mfma_body(
    const uint2* __restrict__ Bu2, const float4* __restrict__ asadv,
    const int* __restrict__ cur, const int* __restrict__ adj,
    const int* __restrict__ ovfD, const int* __restrict__ ovfS,
    const int* __restrict__ ovfCnt, const float* __restrict__ biasF,
    const void* __restrict__ x,
    const int* __restrict__ node0, const unsigned short* __restrict__ Whd,
    const void* sb, const void* pb1, const void* pW2, const void* pb2,
    const void* cb1, const void* cW2, const void* cb2,
    const void* fb1, const void* fW2, const void* fb2,
    const void* bb1, const void* bW2, const void* bb2,
    const void* zb1, const void* zW2, const void* zb2,
    void* __restrict__ outv) {
    __shared__ __align__(16) unsigned short hinS[64 * 168];
    __shared__ __align__(16) unsigned short TwS[4][16 * 168];

    int t = threadIdx.x;
    int g0b = blockIdx.x * 64;
    bf16* outb = (bf16*)outv;
    float* outf = (float*)outv;
#define STORE(idx, val) do { if (F32) outf[idx] = (val); else outb[idx] = __float2bfloat16(val); } while (0)

    int w = t >> 6;
    int lane = t & 63;
    int hl = lane & 31;
    int hb = lane & 32;
    int half = lane >> 5;
    int head = hl >> 4;
    int ln = lane & 15, quad = lane >> 4;
    unsigned* h32 = (unsigned*)hinS;

    // ---- prologue A: dtype cols (raw input cols 0..21 of each root row) ----
    for (int j = t; j < 64 * 20; j += 256) {
        int gl = j / 20, c = j - gl * 20;
        int n0 = node0[g0b + gl];
        int k0 = 2 * c;
        float d0 = (k0 < 22) ? LDWt<F32>(x, (size_t)n0 * 128 + k0) : 0.f;
        float d1 = (k0 + 1 < 22) ? LDWt<F32>(x, (size_t)n0 * 128 + k0 + 1) : 0.f;
        h32[gl * 84 + 64 + c] = ((unsigned)f2us(d1) << 16) | f2us(d0);
    }

    // ---- prologue B: root aggregation (2 graphs per wave-iteration) ----
    for (int pr = 0; pr < 8; ++pr) {
        int gl = w * 16 + pr * 2 + half;   // local graph 0..63
        int node = node0[g0b + gl];

        float4 self = asadv[node];
        float ad0 = self.z, ad1 = self.w;
        float es0 = __expf(leaky(self.x + ad0));
        float es1 = __expf(leaky(self.y + ad1));
        const int* ap = adj + (size_t)node * ADJ_SLOTS;
        int c = cur[node];
        uint2 hvs = Bu2[(size_t)node * 32 + hl];
        float acc0, acc1, acc2, acc3;

        if (c <= 32) {
            int src_r = 0;
            float p0 = 0.f, p1 = 0.f;
            if (hl < c) {
                src_r = ap[hl];
                float4 av = asadv[src_r];
                p0 = __expf(leaky(av.x + ad0));
                p1 = __expf(leaky(av.y + ad1));
            }
            float t0 = p0, t1 = p1;
#pragma unroll
            for (int mask = 1; mask <= 16; mask <<= 1) {
                t0 += __shfl_xor(t0, mask);
                t1 += __shfl_xor(t1, mask);
            }
            float inv0 = 1.f / (es0 + t0 + 1e-16f);
            float inv1 = 1.f / (es1 + t1 + 1e-16f);
            p0 *= inv0;
            p1 *= inv1;
            float aself = head ? es1 * inv1 : es0 * inv0;
            acc0 = aself * lo2f(hvs.x);
            acc1 = aself * hi2f(hvs.x);
            acc2 = aself * lo2f(hvs.y);
            acc3 = aself * hi2f(hvs.y);
            for (int j = 0; j < c; j++) {
                int s2 = __shfl(src_r, hb + j);     // full-exec broadcasts
                float a0 = __shfl(p0, hb + j);
                float a1 = __shfl(p1, hb + j);
                float a = head ? a1 : a0;
                uint2 hv = Bu2[(size_t)s2 * 32 + hl];
                acc0 += a * lo2f(hv.x);
                acc1 += a * hi2f(hv.x);
                acc2 += a * lo2f(hv.y);
                acc3 += a * hi2f(hv.y);
            }
        } else {
            float sum0 = es0, sum1 = es1;
            int cc = min(c, ADJ_SLOTS);
            for (int base = 0; base < cc; base += 32) {
                int i = base + hl;
                float p0 = 0.f, p1 = 0.f;
                if (i < cc) {
                    int s = ap[i];
                    float4 av = asadv[s];
                    p0 = __expf(leaky(av.x + ad0));
                    p1 = __expf(leaky(av.y + ad1));
                }
                float t0 = p0, t1 = p1;
#pragma unroll
                for (int mask = 1; mask <= 16; mask <<= 1) {
                    t0 += __shfl_xor(t0, mask);
                    t1 += __shfl_xor(t1, mask);
                }
                sum0 += t0; sum1 += t1;
            }
            int no = (c > ADJ_SLOTS) ? *ovfCnt : 0;
            for (int oe = 0; oe < no; oe++) {
                if (ovfD[oe] == node) {
                    float4 av = asadv[ovfS[oe]];
                    sum0 += __expf(leaky(av.x + ad0));
                    sum1 += __expf(leaky(av.y + ad1));
                }
            }
            float inv0 = 1.f / (sum0 + 1e-16f);
            float inv1 = 1.f / (sum1 + 1e-16f);
            float aself = head ? es1 * inv1 : es0 * inv0;
            float invh = head ? inv1 : inv0;
            acc0 = aself * lo2f(hvs.x);
            acc1 = aself * hi2f(hvs.x);
            acc2 = aself * lo2f(hvs.y);
            acc3 = aself * hi2f(hvs.y);
            for (int i = 0; i < cc; i++) {
                int s = ap[i];
                float4 av = asadv[s];
                float a = (head ? __expf(leaky(av.y + ad1)) : __expf(leaky(av.x + ad0))) * invh;
                uint2 hv = Bu2[(size_t)s * 32 + hl];
                acc0 += a * lo2f(hv.x);
                acc1 += a * hi2f(hv.x);
                acc2 += a * lo2f(hv.y);
                acc3 += a * hi2f(hv.y);
            }
            for (int oe = 0; oe < no; oe++) {
                if (ovfD[oe] == node) {
                    int s = ovfS[oe];
                    float4 av = asadv[s];
                    float a = (head ? __expf(leaky(av.y + ad1)) : __expf(leaky(av.x + ad0))) * invh;
                    uint2 hv = Bu2[(size_t)s * 32 + hl];
                    acc0 += a * lo2f(hv.x);
                    acc1 += a * hi2f(hv.x);
                    acc2 += a * lo2f(hv.y);
                    acc3 += a * hi2f(hv.y);
                }
            }
        }

        float4 bb4 = ((const float4*)biasF)[hl];  // layer-2 bias, no relu
        h32[gl * 84 + 2 * hl] =
            ((unsigned)f2us(acc1 + bb4.y) << 16) | f2us(acc0 + bb4.x);
        h32[gl * 84 + 2 * hl + 1] =
            ((unsigned)f2us(acc3 + bb4.w) << 16) | f2us(acc2 + bb4.z);
    }
    __syncthreads();

    unsigned short* T = TwS[w];
    int gq = quad * 4;
    int gw0 = g0b + w * 16;

    for (int j = lane; j < 16 * 32; j += 64) {
        int gl = j >> 5, c = j & 31;
        T[gl * 168 + 64 + c] =
            (c < 22) ? hinS[(w * 16 + gl) * 168 + 128 + c] : (unsigned short)0;
    }

    short8 afA[5];
#pragma unroll
    for (int kt = 0; kt < 5; kt++)
        afA[kt] = *(const short8*)&hinS[(w * 16 + ln) * 168 + quad * 8 + kt * 32];
#pragma unroll
    for (int nt = 0; nt < 4; nt++) {
        floatx4 acc = (floatx4){0.f, 0.f, 0.f, 0.f};
        const unsigned short* bp = Whd + (nt * 16 + ln) * 160 + quad * 8;
#pragma unroll
        for (int kt = 0; kt < 5; kt++)
            acc = MF(afA[kt], *(const short8*)(bp + kt * 32), acc);
        float bias = LDWt<F32>(sb, nt * 16 + ln);
#pragma unroll
        for (int r = 0; r < 4; r++)
            T[(gq + r) * 168 + nt * 16 + ln] = f2us(fmaxf(acc[r] + bias, 0.f));
    }
    __syncthreads();

    short8 af20 = *(const short8*)&T[ln * 168 + quad * 8];
    short8 af21 = *(const short8*)&T[ln * 168 + quad * 8 + 32];

#pragma unroll
    for (int k = 0; k < 3; k++) {
        const unsigned short* Bw = Whd + 10240 + k * 4096;
        floatx4 acc[4];
#pragma unroll
        for (int nt = 0; nt < 4; nt++) {
            floatx4 a = (floatx4){0.f, 0.f, 0.f, 0.f};
            const unsigned short* bp = Bw + (nt * 16 + ln) * 64 + quad * 8;
            a = MF(af20, *(const short8*)bp, a);
            a = MF(af21, *(const short8*)(bp + 32), a);
            float b1 = LDWt<F32>(pb1, k * 64 + nt * 16 + ln);
#pragma unroll
            for (int r = 0; r < 4; r++) a[r] = fmaxf(a[r] + b1, 0.f);
            acc[nt] = a;
        }
#pragma unroll
        for (int o = 0; o < 3; o++) {
            float w2[4], part[4];
#pragma unroll
            for (int nt = 0; nt < 4; nt++)
                w2[nt] = LDWt<F32>(pW2, (size_t)k * 192 + (size_t)(nt * 16 + ln) * 3 + o);
#pragma unroll
            for (int r = 0; r < 4; r++)
                part[r] = acc[0][r] * w2[0] + acc[1][r] * w2[1] +
                          acc[2][r] * w2[2] + acc[3][r] * w2[3];
            quadred(part);
            if (ln == 0) {
                float b2 = LDWt<F32>(pb2, k * 3 + o);
#pragma unroll
                for (int r = 0; r < 4; r++)
                    STORE(k * 768 + (gw0 + gq + r) * 3 + o, part[r] + b2);
            }
        }
    }

    {
        const unsigned short* Bw = Whd + 22528;
        floatx4 acc[4];
#pragma unroll
        for (int nt = 0; nt < 4; nt++) {
            floatx4 a = (floatx4){0.f, 0.f, 0.f, 0.f};
            const unsigned short* bp = Bw + (nt * 16 + ln) * 64 + quad * 8;
            a = MF(af20, *(const short8*)bp, a);
            a = MF(af21, *(const short8*)(bp + 32), a);
            float b1 = LDWt<F32>(cb1, nt * 16 + ln);
#pragma unroll
            for (int r = 0; r < 4; r++) a[r] = fmaxf(a[r] + b1, 0.f);
            acc[nt] = a;
        }
#pragma unroll
        for (int o = 0; o < 5; o++) {
            float w2[4], part[4];
#pragma unroll
            for (int nt = 0; nt < 4; nt++)
                w2[nt] = LDWt<F32>(cW2, (size_t)(nt * 16 + ln) * 5 + o);
#pragma unroll
            for (int r = 0; r < 4; r++)
                part[r] = acc[0][r] * w2[0] + acc[1][r] * w2[1] +
                          acc[2][r] * w2[2] + acc[3][r] * w2[3];
            quadred(part);
            if (ln == 0) {
                float b2 = LDWt<F32>(cb2, o);
#pragma unroll
                for (int r = 0; r < 4; r++) {
                    float v = part[r] + b2;
                    T[(gq + r) * 168 + 86 + o] = f2us(v);
                    STORE(2304 + (gw0 + gq + r) * 5 + o, v);
                }
            }
        }
    }

#pragma unroll
    for (int k = 0; k < 2; k++) {
        const unsigned short* Bw = Whd + 26624 + k * 4096;
        floatx4 acc[4];
#pragma unroll
        for (int nt = 0; nt < 4; nt++) {
            floatx4 a = (floatx4){0.f, 0.f, 0.f, 0.f};
            const unsigned short* bp = Bw + (nt * 16 + ln) * 64 + quad * 8;
            a = MF(af20, *(const short8*)bp, a);
            a = MF(af21, *(const short8*)(bp + 32), a);
            float b1 = LDWt<F32>(fb1, k * 64 + nt * 16 + ln);
#pragma unroll
            for (int r = 0; r < 4; r++) a[r] = fmaxf(a[r] + b1, 0.f);
            acc[nt] = a;
        }
        float w2[4], part[4];
#pragma unroll
        for (int nt = 0; nt < 4; nt++)
            w2[nt] = LDWt<F32>(fW2, (size_t)k * 64 + nt * 16 + ln);
#pragma unroll
        for (int r = 0; r < 4; r++)
            part[r] = acc[0][r] * w2[0] + acc[1][r] * w2[1] +
                      acc[2][r] * w2[2] + acc[3][r] * w2[3];
        quadred(part);
        if (ln == 0) {
            float b2 = LDWt<F32>(fb2, k);
#pragma unroll
            for (int r = 0; r < 4; r++) {
                float v = part[r] + b2;
                T[(gq + r) * 168 + 91 + k] = f2us(v);
                STORE(3584 + k * 256 + (gw0 + gq + r), v);
            }
        }
    }
    __syncthreads();

    short8 af3 = *(const short8*)&T[ln * 168 + 64 + quad * 8];

    {
        const unsigned short* Bw = Whd + 34816;
        floatx4 acc[4];
#pragma unroll
        for (int nt = 0; nt < 4; nt++) {
            floatx4 a = (floatx4){0.f, 0.f, 0.f, 0.f};
            const unsigned short* bp = Bw + (nt * 16 + ln) * 96 + quad * 8;
            a = MF(af20, *(const short8*)bp, a);
            a = MF(af21, *(const short8*)(bp + 32), a);
            a = MF(af3, *(const short8*)(bp + 64), a);
            float b1 = LDWt<F32>(bb1, nt * 16 + ln);
#pragma unroll
            for (int r = 0; r < 4; r++) a[r] = fmaxf(a[r] + b1, 0.f);
            acc[nt] = a;
        }
        float w2[4], part[4];
#pragma unroll
        for (int nt = 0; nt < 4; nt++)
            w2[nt] = LDWt<F32>(bW2, nt * 16 + ln);
#pragma unroll
        for (int r = 0; r < 4; r++)
            part[r] = acc[0][r] * w2[0] + acc[1][r] * w2[1] +
                      acc[2][r] * w2[2] + acc[3][r] * w2[3];
        quadred(part);
        if (ln == 0) {
            float b2 = LDWt<F32>(bb2, 0);
#pragma unroll
            for (int r = 0; r < 4; r++) {
                float v = part[r] + b2;
                T[(gq + r) * 168 + 93] = f2us(v);
                STORE(4096 + (gw0 + gq + r), v);
            }
        }
    }
    __syncthreads();

    af3 = *(const short8*)&T[ln * 168 + 64 + quad * 8];

    {
        const unsigned short* Bw = Whd + 40960;
        floatx4 acc[4];
#pragma unroll
        for (int nt = 0; nt < 4; nt++) {
            floatx4 a = (floatx4){0.f, 0.f, 0.f, 0.f};
            const unsigned short* bp = Bw + (nt * 16 + ln) * 96 + quad * 8;
            a = MF(af20, *(const short8*)bp, a);
            a = MF(af21, *(const short8*)(bp + 32), a);
            a = MF(af3, *(const short8*)(bp + 64), a);
            float b1 = LDWt<F32>(zb1, nt * 16 + ln);
#pragma unroll
            for (int r = 0; r < 4; r++) a[r] = fmaxf(a[r] + b1, 0.f);
            acc[nt] = a;
        }
#pragma unroll
        for (int o = 0; o < 8; o++) {
            float w2[4], part[4];
#pragma unroll
            for (int nt = 0; nt < 4; nt++)
                w2[nt] = LDWt<F32>(zW2, (size_t)(nt * 16 + ln) * 8 + o);
#pragma unroll
            for (int r = 0; r < 4; r++)
                part[r] = acc[0][r] * w2[0] + acc[1][r] * w2[1] +
                          acc[2][r] * w2[2] + acc[3][r] * w2[3];
            quadred(part);
            if (ln == 0) {
                float b2 = LDWt<F32>(zb2, o);
#pragma unroll
                for (int r = 0; r < 4; r++)
                    STORE(4352 + (gw0 + gq + r) * 8 + o, part[r] + b2);
            }
        }
    }
#undef STORE
}

__global__ __launch_bounds__(256) void k_heads_mfma(
    const uint2* __restrict__ Bu2, const float4* __restrict__ asadv,
    const int* __restrict__ cur, const int* __restrict__ adj,
    const int* __restrict__ ovfD, const int* __restrict__ ovfS,
    const int* __restrict__ ovfCnt, const float* __restrict__ biasF,
    const void* __restrict__ x,
    const int* __restrict__ node0, const unsigned short* __restrict__ Whd,
    const void* sb, const void* pb1, const void* pW2, const void* pb2,
    const void* cb1, const void* cW2, const void* cb2,
    const void* fb1, const void* fW2, const void* fb2,
    const void* bb1, const void* bW2, const void* bb2,
    const void* zb1, const void* zW2, const void* zb2,
    void* __restrict__ outv, const int* __restrict__ flagd) {
    if (*flagd)
        heads_mfma_body<1>(Bu2, asadv, cur, adj, ovfD, ovfS, ovfCnt, biasF, x,
                           node0, Whd, sb, pb1, pW2, pb2, cb1, cW2, cb2,
                           fb1, fW2, fb2, bb1, bW2, bb2, zb1, zW2, zb2, outv);
    else
        heads_mfma_body<0>(Bu2, asadv, cur, adj, ovfD, ovfS, ovfCnt, biasF, x,
                           node0, Whd, sb, pb1, pW2, pb2, cb1, cW2, cb2,
                           fb1, fW2, fb2, bb1, bW2, bb2, zb1, zW2, zb2, outv);
}

// ---------------- host ----------------

extern "C" void kernel_launch(void* const* d_in, const int* in_sizes, int n_in,
                              void* d_out, int out_size, void* d_ws, size_t ws_size,
                              hipStream_t stream) {
    const void* x     = d_in[0];
    const int*  ei    = (const int*)d_in[1];
    const int*  batch = (const int*)d_in[2];

    int N = in_sizes[0] / 128;
    int E = in_sizes[1] / 2;

    char* w = (char*)d_ws;
    float4* asad = (float4*)w;              w += (size_t)N * 16;
    unsigned short* A = (unsigned short*)w; w += (size_t)N * 128 * 2;
    unsigned short* B = (unsigned short*)w; w += (size_t)N * 128 * 2;
    unsigned short* Wt = (unsigned short*)w; w += 3 * 16384 * 2;
    unsigned short* Whd = (unsigned short*)w; w += 47104 * 2;
    float* asF = (float*)w;                 w += 384 * 4;
    float* adF = (float*)w;                 w += 384 * 4;
    float* bF = (float*)w;                  w += 384 * 4;
    int* wl1 = (int*)w;                     w += (size_t)N * 4;
    int* wl2 = (int*)w;                     w += (size_t)N * 4;
    int* adj = (int*)w;                     w += (size_t)N * ADJ_SLOTS * 4;
    int* ovfD = (int*)w;                    w += (size_t)E * 4;
    int* ovfS = (int*)w;                    w += (size_t)E * 4;
    int* node0 = (int*)w;                   w += 256 * 4;
    // ---- contiguous zero-region (zeroed by k_detect_zero) ----
    char* zbase = w;
    int* cur = (int*)w;                     w += (size_t)N * 4;
    unsigned char* flag1 = (unsigned char*)w; w += (size_t)N;
    int* nact = (int*)w;                    w += 64 * 4;  // [0]=|wl1|, [32]=|wl2|
    int* ovfCnt = (int*)w;                  w += 64;
    size_t zbytes = (size_t)N * 5 + 64 * 4 + 64;  // multiple of 16
    // ---- densely-written / written-once (no zeroing needed) ----
    int* flagd = (int*)w;                   w += 64;
    unsigned char* rootb = (unsigned char*)w; w += (size_t)N;
    unsigned char* flag2 = (unsigned char*)w; w += (size_t)N;

    int nb = (N + 255) / 256;
    int nvec = N * 16;
    int nbx8 = (nvec + 255) / 256;
    int nbE = (E + 255) / 256;
    int zBlocks = (int)((zbytes + 4095) / 4096);

    // K1: dtype probe -> flagd, zero {cur,flag1,nact,ovfCnt}, node0/rootb/flag2
    k_detect_zero<<<1 + zBlocks + nb, 256, 0, stream>>>(
        x, flagd, zbase, zbytes, batch, node0, rootb, flag2, N, zBlocks);

    // K2: mark2 edge scan + weight transposes + x-convert (direct-indexed)
    k_prep<<<nbE + 194 + 184 + nbx8, 256, 0, stream>>>(
        x, A, nvec, d_in[3], Wt, d_in[4], d_in[5], d_in[6],
        asF, adF, bF,
        d_in[7], d_in[9], d_in[13], d_in[17], d_in[21], d_in[25], Whd,
        ei, rootb, flag2, E, flagd, nbE);

    // K3: layer-0 GEMM (grid-stride tiles, LDS-staged Wt) + mark1
    k_gemm0_mark<<<nbE + nb + 800, 256, 0, stream>>>(
        A, x, Wt, B, asad, asF, adF, N, ei, flag2, flag1, E, nbE, nb, flagd);

    // K4: cursor scatter into 128-slot adj (+overflow) + atomic-append worklists
    k_scatter_wl<<<nbE + nb, 256, 0, stream>>>(
        ei, cur, flag1, flag2, adj, ovfD, ovfS, ovfCnt, wl1, wl2, nact, E, N, nbE);

    // K5: layer-0 agg over wl1 (grid-stride waves)
    k_gat_agg<<<2048, 256, 0, stream>>>(
        (const uint2*)B, asad, cur, adj, ovfD, ovfS, ovfCnt, bF, (uint2*)A,
        nact, 1, wl1);

    // K6: layer-1 gather-GEMM over wl1
    k_gemm_mfma<<<512, 256, 0, stream>>>(
        A, Wt + 16384, B, asad, asF + 128, adF + 128, N, wl1, nact);

    // K7: layer-1 agg over wl2
    k_gat_agg<<<512, 256, 0, stream>>>(
        (const uint2*)B, asad, cur, adj, ovfD, ovfS, ovfCnt, bF + 128, (uint2*)A,
        nact + 32, 1, wl2);

    // K8: layer-2 gather-GEMM over wl2
    k_gemm_mfma<<<128, 256, 0, stream>>>(
        A, Wt + 2 * 16384, B, asad, asF + 256, adF + 256, N, wl2, nact + 32);

    // K9: heads (fused root aggregation + MFMA-batched MLP chain)
    k_heads_mfma<<<4, 256, 0, stream>>>(
        (const uint2*)B, asad, cur, adj, ovfD, ovfS, ovfCnt, bF + 256, x, node0, Whd,
        d_in[8], d_in[10], d_in[11], d_in[12],
        d_in[14], d_in[15], d_in[16],
        d_in[18], d_in[19], d_in[20],
        d_in[22], d_in[23], d_in[24],
        d_in[26], d_in[27], d_in[28],
        d_out, flagd);
}

// Round 12
// 313.199 us; speedup vs baseline: 1.1258x; 1.1258x over previous
//
#include <hip/hip_runtime.h>
#include <hip/hip_bf16.h>

typedef __hip_bfloat16 bf16;
typedef __attribute__((ext_vector_type(8))) short short8;
typedef __attribute__((ext_vector_type(4))) float floatx4;

#define MF(a, b, c) __builtin_amdgcn_mfma_f32_16x16x32_bf16(a, b, c, 0, 0, 0)
#define ADJ_SLOTS 128

__device__ __forceinline__ float b2f(bf16 v) { return __bfloat162float(v); }
__device__ __forceinline__ unsigned short f2us(float f) {
    bf16 h = __float2bfloat16(f);
    return *(unsigned short*)&h;
}
__device__ __forceinline__ float lo2f(unsigned hv) { return __uint_as_float(hv << 16); }
__device__ __forceinline__ float hi2f(unsigned hv) { return __uint_as_float(hv & 0xffff0000u); }
__device__ __forceinline__ float leaky(float v) { return v > 0.f ? v : 0.2f * v; }

__device__ __forceinline__ float ldw(const void* p, size_t i, int f32) {
    return f32 ? ((const float*)p)[i] : b2f(((const bf16*)p)[i]);
}

template <int F32>
__device__ __forceinline__ float LDWt(const void* p, size_t i) {
    return F32 ? ((const float*)p)[i] : b2f(((const bf16*)p)[i]);
}

// reduce part[0..3] over the 16 lanes of a quad-group (masks 1,2,4,8)
__device__ __forceinline__ void quadred(float part[4]) {
#pragma unroll
    for (int m = 1; m <= 8; m <<= 1)
#pragma unroll
        for (int r = 0; r < 4; r++) part[r] += __shfl_xor(part[r], m);
}

// ---------------- K1: dtype detect + workspace zero + node0/rootb/flag2 ------
// (R7 lesson: no cooperative grid.sync; R11 lesson: don't fuse latency-bound
// work into low-parallelism kernels — a launch boundary is cheaper.)
__global__ void k_detect_zero(const void* x, int* flagd, char* zbase, size_t zbytes,
                              const int* __restrict__ batch, int* __restrict__ node0,
                              unsigned char* __restrict__ rootb,
                              unsigned char* __restrict__ flag2, int N, int zBlocks) {
    int b = blockIdx.x;
    int t = threadIdx.x;
    if (b == 0) {
        __shared__ int sbad;
        if (t == 0) sbad = 0;
        __syncthreads();
        const bf16* xb = (const bf16*)x;
        int bad = 0;
#pragma unroll
        for (int j = 0; j < 16; j++) {
            float v = b2f(xb[t * 16 + j]);  // sample elements 0..4095
            if (!(fabsf(v) < 1e10f)) bad = 1;
        }
        if (bad) sbad = 1;  // benign same-value race
        __syncthreads();
        if (t == 0) flagd[0] = sbad;
    } else if (b < 1 + zBlocks) {
        size_t off = (size_t)(b - 1) * 4096 + (size_t)t * 16;
        if (off < zbytes) *(uint4*)(zbase + off) = make_uint4(0u, 0u, 0u, 0u);
    } else {
        int i = (b - 1 - zBlocks) * 256 + t;
        if (i < N) {
            int bb = batch[i];
            int isroot = (i == 0) || (batch[i - 1] != bb);
            rootb[i] = (unsigned char)isroot;  // dense init: no pre-zero needed
            flag2[i] = (unsigned char)isroot;
            if (isroot) node0[bb] = i;
        }
    }
}

// ---------------- K2: prep — mark2 edge scan, Wt transpose, head-W1
// transposes, small weights, x->bf16 (f32 path; direct-indexed — R9 lesson:
// grid-stride starved the 78 MB convert) ----------------
__global__ void k_prep(const void* __restrict__ x, unsigned short* __restrict__ Ab,
                       int nvec,
                       const void* __restrict__ gw, unsigned short* __restrict__ Wt,
                       const void* as_, const void* ad_, const void* b_,
                       float* asF, float* adF, float* bF,
                       const void* sW_, const void* pW1_, const void* cW1_,
                       const void* fW1_, const void* bW1_, const void* zW1_,
                       unsigned short* __restrict__ Whd,
                       const int* __restrict__ ei, const unsigned char* __restrict__ rootb,
                       unsigned char* __restrict__ flag2, int E,
                       const int* __restrict__ flagd, int nbE) {
    int b = blockIdx.x;
    int t = threadIdx.x;
    if (b < nbE) {
        // mark2: src feeds a graph root -> layer-2 frontier (only SETS bits)
        int e = b * 256 + t;
        if (e < E && rootb[ei[E + e]]) flag2[ei[e]] = 1;
        return;
    }
    int f32 = *flagd;
    b -= nbE;
    if (b < 192) {
        int i = b * 256 + t;  // exactly 3*16384
        int l = i >> 14, rem = i & 16383, n = rem >> 7, k = rem & 127;
        Wt[i] = f2us(ldw(gw, (size_t)l * 16384 + (size_t)k * 128 + n, f32));
    } else if (b < 194) {
        int i = (b - 192) * 256 + t;
        if (i < 384) {
            asF[i] = ldw(as_, i, f32);
            adF[i] = ldw(ad_, i, f32);
            bF[i] = ldw(b_, i, f32);
        }
    } else if (b < 194 + 184) {
        // transposed head W1s -> Whd (bf16, col-major [n][k], zero-padded K)
        // layout: sWt[64][160] @0; pW1t 3x[64][64] @10240; cW1t @22528;
        //         fW1t 2x @26624; bW1t[64][96] @34816; zW1t[64][96] @40960.
        int i = (b - 194) * 256 + t;  // 0..47103
        float v;
        if (i < 10240) {
            int n = i / 160, k = i - n * 160;
            v = (k < 150) ? ldw(sW_, (size_t)k * 64 + n, f32) : 0.f;
        } else if (i < 22528) {
            int j = i - 10240;
            int kk = j >> 12, r = j & 4095, n = r >> 6, k = r & 63;
            v = ldw(pW1_, (size_t)kk * 4096 + (size_t)k * 64 + n, f32);
        } else if (i < 26624) {
            int j = i - 22528;
            int n = j >> 6, k = j & 63;
            v = ldw(cW1_, (size_t)k * 64 + n, f32);
        } else if (i < 34816) {
            int j = i - 26624;
            int kk = j >> 12, r = j & 4095, n = r >> 6, k = r & 63;
            v = ldw(fW1_, (size_t)kk * 4096 + (size_t)k * 64 + n, f32);
        } else if (i < 40960) {
            int j = i - 34816;
            int n = j / 96, k = j - n * 96;
            v = (k < 93) ? ldw(bW1_, (size_t)k * 64 + n, f32) : 0.f;
        } else {
            int j = i - 40960;
            int n = j / 96, k = j - n * 96;
            v = (k < 94) ? ldw(zW1_, (size_t)k * 64 + n, f32) : 0.f;
        }
        Whd[i] = f2us(v);
    } else {
        // x -> bf16 conversion (f32 storage path); one uint4 per thread
        if (!f32) return;
        int i = (b - 194 - 184) * 256 + t;
        if (i < nvec) {
            float4 a = ((const float4*)x)[2 * i];
            float4 c = ((const float4*)x)[2 * i + 1];
            uint4 o;
            o.x = ((unsigned)f2us(a.y) << 16) | f2us(a.x);
            o.y = ((unsigned)f2us(a.w) << 16) | f2us(a.z);
            o.z = ((unsigned)f2us(c.y) << 16) | f2us(c.x);
            o.w = ((unsigned)f2us(c.w) << 16) | f2us(c.z);
            ((uint4*)Ab)[i] = o;
        }
    }
}

// ---------------- K4: cursor scatter + ATOMIC-APPEND worklists ----------------
// No scan kernel: adj offsets implicit (node*ADJ_SLOTS); worklists built by
// per-wave-coalesced atomic append (order nondeterministic; results identical).
// nactp[0] = |wl1| ; nactp[32] = |wl2| (128B apart to avoid line contention).
__global__ void k_scatter_wl(const int* __restrict__ ei,
                             int* __restrict__ cur,
                             const unsigned char* __restrict__ flag1,
                             const unsigned char* __restrict__ flag2,
                             int* __restrict__ adj,
                             int* __restrict__ ovfD, int* __restrict__ ovfS,
                             int* __restrict__ ovfCnt,
                             int* __restrict__ wl1, int* __restrict__ wl2,
                             int* __restrict__ nactp,
                             int E, int N, int eBlocks) {
    int b = blockIdx.x;
    if (b < eBlocks) {
        int e = b * 256 + threadIdx.x;
        if (e >= E) return;
        int d = ei[E + e];
        if (!flag1[d]) return;
        int slot = atomicAdd(&cur[d], 1);
        if (slot < ADJ_SLOTS) {
            adj[(size_t)d * ADJ_SLOTS + slot] = ei[e];
        } else {
            int o = atomicAdd(ovfCnt, 1);
            if (o < E) { ovfD[o] = d; ovfS[o] = ei[e]; }
        }
    } else {
        int i = (b - eBlocks) * 256 + threadIdx.x;
        if (i < N) {
            if (flag1[i]) wl1[atomicAdd(&nactp[0], 1)] = i;
            if (flag2[i]) wl2[atomicAdd(&nactp[32], 1)] = i;
        }
    }
}

// ---------------- MFMA GEMM body: LDS-staged Wt, grid-stride over tiles ------
__device__ __forceinline__ void gemm_body(
    const unsigned short* __restrict__ Asrc, const unsigned short* __restrict__ Wt,
    unsigned short* __restrict__ Bb, float4* __restrict__ asadv,
    const float* __restrict__ asF, const float* __restrict__ adF, int N,
    const int* __restrict__ wl, const int* __restrict__ nactp,
    int bb0, int bstride) {
    __shared__ __align__(16) unsigned short Ws[128 * 136];
    __shared__ __align__(16) unsigned short Cs[64 * 136];

    int t = threadIdx.x;
    int nact = wl ? *nactp : N;
    if (bb0 * 64 >= nact) return;  // idle block: exit before staging

    {
        const uint4* src = (const uint4*)Wt;  // 2048 uint4
#pragma unroll
        for (int k = 0; k < 8; k++) {
            int j = t + k * 256;
            int row = j >> 4, c16 = j & 15;
            *(uint4*)&Ws[row * 136 + c16 * 8] = src[j];
        }
    }
    __syncthreads();

    int lane = t & 63;
    int w = t >> 6;
    int ln = lane & 15;
    int quad = lane >> 4;

    for (int bb = bb0; bb * 64 < nact; bb += bstride) {
        int r0 = bb * 64;
        int idx = r0 + w * 16 + ln;
        bool valid = idx < nact;
        int arow = idx < N ? idx : N - 1;
        if (wl) arow = valid ? wl[idx] : 0;
        bool wave_active = __any((int)valid);

        if (wave_active) {
            const unsigned short* ap = Asrc + (size_t)arow * 128 + quad * 8;

            short8 afrag[4];
            if (valid) {
#pragma unroll
                for (int kt = 0; kt < 4; kt++)
                    afrag[kt] = *(const short8*)(ap + kt * 32);
            } else {
#pragma unroll
                for (int kt = 0; kt < 4; kt++)
                    afrag[kt] = (short8){0, 0, 0, 0, 0, 0, 0, 0};
            }

            floatx4 acc[8];
#pragma unroll
            for (int nt = 0; nt < 8; nt++) acc[nt] = (floatx4){0.f, 0.f, 0.f, 0.f};

#pragma unroll
            for (int nt = 0; nt < 8; nt++) {
                const unsigned short* wp = Ws + (nt * 16 + ln) * 136 + quad * 8;
#pragma unroll
                for (int kt = 0; kt < 4; kt++) {
                    short8 bfrag = *(const short8*)(wp + kt * 32);
                    acc[nt] = MF(afrag[kt], bfrag, acc[nt]);
                }
            }

            float as0[4] = {0, 0, 0, 0}, as1[4] = {0, 0, 0, 0};
            float ad0[4] = {0, 0, 0, 0}, ad1[4] = {0, 0, 0, 0};
#pragma unroll
            for (int nt = 0; nt < 8; nt++) {
                float asc = asF[nt * 16 + ln];
                float adc = adF[nt * 16 + ln];
#pragma unroll
                for (int r = 0; r < 4; r++) {
                    float v = acc[nt][r];
                    Cs[(w * 16 + quad * 4 + r) * 136 + nt * 16 + ln] = f2us(v);
                    if (nt < 4) { as0[r] += v * asc; ad0[r] += v * adc; }
                    else        { as1[r] += v * asc; ad1[r] += v * adc; }
                }
            }
#pragma unroll
            for (int mask = 1; mask <= 8; mask <<= 1) {
#pragma unroll
                for (int r = 0; r < 4; r++) {
                    as0[r] += __shfl_xor(as0[r], mask);
                    as1[r] += __shfl_xor(as1[r], mask);
                    ad0[r] += __shfl_xor(ad0[r], mask);
                    ad1[r] += __shfl_xor(ad1[r], mask);
                }
            }
            if (ln == 0) {
#pragma unroll
                for (int r = 0; r < 4; r++) {
                    int idx3 = r0 + w * 16 + quad * 4 + r;
                    if (idx3 < nact) {
                        int row = wl ? wl[idx3] : idx3;
                        asadv[row] = make_float4(as0[r], as1[r], ad0[r], ad1[r]);
                    }
                }
            }
        }
        __syncthreads();

        {
            int idx2 = r0 + (t >> 2);
            int cseg = (t & 3) * 32;
            if (idx2 < nact) {
                int grow = wl ? wl[idx2] : idx2;
                const short8* srcp = (const short8*)&Cs[(t >> 2) * 136 + cseg];
                short8* dstp = (short8*)&Bb[(size_t)grow * 128 + cseg];
#pragma unroll
                for (int u = 0; u < 4; u++) dstp[u] = srcp[u];
            }
        }
        __syncthreads();  // Cs consumed before next tile overwrites it
    }
}

__global__ __launch_bounds__(256) void k_gemm_mfma(
    const unsigned short* __restrict__ Ab, const unsigned short* __restrict__ Wt,
    unsigned short* __restrict__ Bb, float4* __restrict__ asadv,
    const float* __restrict__ asF, const float* __restrict__ adF, int N,
    const int* __restrict__ wl, const int* __restrict__ nactp) {
    gemm_body(Ab, Wt, Bb, asadv, asF, adF, N, wl, nactp, blockIdx.x, gridDim.x);
}

// K3: layer-0 GEMM (reads x directly when bf16) fused with mark1
__global__ __launch_bounds__(256) void k_gemm0_mark(
    const unsigned short* __restrict__ Ab, const void* __restrict__ xraw,
    const unsigned short* __restrict__ Wt,
    unsigned short* __restrict__ Bb, float4* __restrict__ asadv,
    const float* __restrict__ asF, const float* __restrict__ adF, int N,
    const int* __restrict__ ei, const unsigned char* __restrict__ flag2,
    unsigned char* __restrict__ flag1, int E, int markE, int markN,
    const int* __restrict__ flagd) {
    int b = blockIdx.x;
    if (b < markE) {
        int e = b * 256 + threadIdx.x;
        if (e < E && flag2[ei[E + e]]) flag1[ei[e]] = 1;
        return;
    }
    if (b < markE + markN) {
        int i = (b - markE) * 256 + threadIdx.x;
        if (i < N && flag2[i]) flag1[i] = 1;
        return;
    }
    const unsigned short* Asrc = *flagd ? Ab : (const unsigned short*)xraw;
    gemm_body(Asrc, Wt, Bb, asadv, asF, adF, N, nullptr, nullptr,
              b - markE - markN, gridDim.x - markE - markN);
}

// ---------------- GAT aggregation: grid-stride waves over a worklist ---------
// byidx: compact output (row = worklist index); nfix: host-known count.
__global__ void k_gat_agg(const uint2* __restrict__ Bu2, const float4* __restrict__ asadv,
                          const int* __restrict__ cur, const int* __restrict__ adj,
                          const int* __restrict__ ovfD, const int* __restrict__ ovfS,
                          const int* __restrict__ ovfCnt,
                          const float* __restrict__ biasF,
                          uint2* __restrict__ Au2,
                          const int* __restrict__ nactp, int nfix, int dorelu, int byidx,
                          const int* __restrict__ wl) {
    int totWaves = (gridDim.x * blockDim.x) >> 6;
    int wave0 = (blockIdx.x * blockDim.x + threadIdx.x) >> 6;
    int lane = threadIdx.x & 63;
    int hl = lane & 31;          // lane within node-half
    int hb = lane & 32;          // shfl broadcast base for this half
    int half = lane >> 5;
    int head = hl >> 4;
    int n = nfix ? nfix : *nactp;

    for (int wv = wave0; wv * 2 < n; wv += totWaves) {
        int idx = wv * 2 + half;
        if (idx >= n) continue;  // half-wave masked; shfls stay in-half
        int node = wl[idx];

        float4 self = asadv[node];
        float ad0 = self.z, ad1 = self.w;
        float es0 = __expf(leaky(self.x + ad0));
        float es1 = __expf(leaky(self.y + ad1));

        const int* ap = adj + (size_t)node * ADJ_SLOTS;
        int c = cur[node];
        uint2 hvs = Bu2[(size_t)node * 32 + hl];
        float acc0, acc1, acc2, acc3;

        if (c <= 32) {
            // ---- fast path ----
            int src_r = 0;
            float p0 = 0.f, p1 = 0.f;
            if (hl < c) {
                src_r = ap[hl];
                float4 av = asadv[src_r];
                p0 = __expf(leaky(av.x + ad0));
                p1 = __expf(leaky(av.y + ad1));
            }
            float t0 = p0, t1 = p1;
#pragma unroll
            for (int mask = 1; mask <= 16; mask <<= 1) {
                t0 += __shfl_xor(t0, mask);
                t1 += __shfl_xor(t1, mask);
            }
            float inv0 = 1.f / (es0 + t0 + 1e-16f);
            float inv1 = 1.f / (es1 + t1 + 1e-16f);
            p0 *= inv0;
            p1 *= inv1;
            float aself = head ? es1 * inv1 : es0 * inv0;
            acc0 = aself * lo2f(hvs.x);
            acc1 = aself * hi2f(hvs.x);
            acc2 = aself * lo2f(hvs.y);
            acc3 = aself * hi2f(hvs.y);

            uint2 hq[4];
#pragma unroll
            for (int j = 0; j < 4; j++) {
                int s2 = __shfl(src_r, hb + j);
                hq[j] = make_uint2(0u, 0u);
                if (j < c) hq[j] = Bu2[(size_t)s2 * 32 + hl];
            }

            for (int base = 0; base < c; base += 4) {
                uint2 cu[4];
                float av4[4];
#pragma unroll
                for (int j = 0; j < 4; j++) {
                    cu[j] = hq[j];
                    int idx2 = (base + j) & 31;
                    float a0 = __shfl(p0, hb + idx2);   // full-exec broadcasts
                    float a1 = __shfl(p1, hb + idx2);
                    float a = head ? a1 : a0;
                    av4[j] = (base + j < c) ? a : 0.f;
                }
#pragma unroll
                for (int j = 0; j < 4; j++) {
                    int nx = base + 4 + j;
                    int s2 = __shfl(src_r, hb + (nx & 31));
                    if (nx < c) hq[j] = Bu2[(size_t)s2 * 32 + hl];
                }
#pragma unroll
                for (int j = 0; j < 4; j++) {
                    acc0 += av4[j] * lo2f(cu[j].x);
                    acc1 += av4[j] * hi2f(cu[j].x);
                    acc2 += av4[j] * lo2f(cu[j].y);
                    acc3 += av4[j] * hi2f(cu[j].y);
                }
            }
        } else {
            // ---- slow path (rare, c>32): recompute alphas, no staging ----
            float sum0 = es0, sum1 = es1;
            int cc = min(c, ADJ_SLOTS);
            for (int base = 0; base < cc; base += 32) {
                int i = base + hl;
                float p0 = 0.f, p1 = 0.f;
                if (i < cc) {
                    int s = ap[i];
                    float4 av = asadv[s];
                    p0 = __expf(leaky(av.x + ad0));
                    p1 = __expf(leaky(av.y + ad1));
                }
                float t0 = p0, t1 = p1;
#pragma unroll
                for (int mask = 1; mask <= 16; mask <<= 1) {
                    t0 += __shfl_xor(t0, mask);
                    t1 += __shfl_xor(t1, mask);
                }
                sum0 += t0; sum1 += t1;
            }
            int no = (c > ADJ_SLOTS) ? *ovfCnt : 0;
            for (int oe = 0; oe < no; oe++) {
                if (ovfD[oe] == node) {
                    float4 av = asadv[ovfS[oe]];
                    sum0 += __expf(leaky(av.x + ad0));
                    sum1 += __expf(leaky(av.y + ad1));
                }
            }
            float inv0 = 1.f / (sum0 + 1e-16f);
            float inv1 = 1.f / (sum1 + 1e-16f);
            float aself = head ? es1 * inv1 : es0 * inv0;
            float invh = head ? inv1 : inv0;
            acc0 = aself * lo2f(hvs.x);
            acc1 = aself * hi2f(hvs.x);
            acc2 = aself * lo2f(hvs.y);
            acc3 = aself * hi2f(hvs.y);
            for (int i = 0; i < cc; i++) {
                int s = ap[i];
                float4 av = asadv[s];
                float a = (head ? __expf(leaky(av.y + ad1)) : __expf(leaky(av.x + ad0))) * invh;
                uint2 hv = Bu2[(size_t)s * 32 + hl];
                acc0 += a * lo2f(hv.x);
                acc1 += a * hi2f(hv.x);
                acc2 += a * lo2f(hv.y);
                acc3 += a * hi2f(hv.y);
            }
            for (int oe = 0; oe < no; oe++) {
                if (ovfD[oe] == node) {
                    int s = ovfS[oe];
                    float4 av = asadv[s];
                    float a = (head ? __expf(leaky(av.y + ad1)) : __expf(leaky(av.x + ad0))) * invh;
                    uint2 hv = Bu2[(size_t)s * 32 + hl];
                    acc0 += a * lo2f(hv.x);
                    acc1 += a * hi2f(hv.x);
                    acc2 += a * lo2f(hv.y);
                    acc3 += a * hi2f(hv.y);
                }
            }
        }

        float4 bb4 = ((const float4*)biasF)[hl];
        float q0 = acc0 + bb4.x;
        float q1 = acc1 + bb4.y;
        float q2 = acc2 + bb4.z;
        float q3 = acc3 + bb4.w;
        if (dorelu) {
            q0 = fmaxf(q0, 0.f); q1 = fmaxf(q1, 0.f);
            q2 = fmaxf(q2, 0.f); q3 = fmaxf(q3, 0.f);
        }
        Au2[(size_t)(byidx ? idx : node) * 32 + hl] =
            make_uint2(((unsigned)f2us(q1) << 16) | f2us(q0),
                       ((unsigned)f2us(q3) << 16) | f2us(q2));
    }
}

// ---------------- heads: MFMA-batched over graphs (verified R6/R8/R10) -------
template <int F32>
__device__ void heads_mfma_body(
    const unsigned* __restrict__ hroot32, const void* __restrict__ x,
    const int* __restrict__ node0, const unsigned short* __restrict__ Whd,
    const void* sb, const void* pb1, const void* pW2, const void* pb2,
    const void* cb1, const void* cW2, const void* cb2,
    const void* fb1, const void* fW2, const void* fb2,
    const void* bb1, const void* bW2, const void* bb2,
    const void* zb1, const void* zW2, const void* zb2,
    void* __restrict__ outv) {
    __shared__ __align__(16) unsigned short hinS[64 * 168];
    __shared__ __align__(16) unsigned short TwS[4][16 * 168];

    int t = threadIdx.x;
    int g0b = blockIdx.x * 64;
    bf16* outb = (bf16*)outv;
    float* outf = (float*)outv;
#define STORE(idx, val) do { if (F32) outf[idx] = (val); else outb[idx] = __float2bfloat16(val); } while (0)

    {
        unsigned* h32 = (unsigned*)hinS;
        for (int j = t; j < 64 * 64; j += 256) {
            int gl = j >> 6, c = j & 63;
            h32[gl * 84 + c] = hroot32[(size_t)(g0b + gl) * 64 + c];
        }
        for (int j = t; j < 64 * 20; j += 256) {
            int gl = j / 20, c = j - gl * 20;
            int n0 = node0[g0b + gl];
            int k0 = 2 * c;
            float d0 = (k0 < 22) ? LDWt<F32>(x, (size_t)n0 * 128 + k0) : 0.f;
            float d1 = (k0 + 1 < 22) ? LDWt<F32>(x, (size_t)n0 * 128 + k0 + 1) : 0.f;
            h32[gl * 84 + 64 + c] = ((unsigned)f2us(d1) << 16) | f2us(d0);
        }
    }
    __syncthreads();

    int w = t >> 6;
    int lane = t & 63;
    int ln = lane & 15, quad = lane >> 4;
    unsigned short* T = TwS[w];
    int gq = quad * 4;
    int gw0 = g0b + w * 16;

    for (int j = lane; j < 16 * 32; j += 64) {
        int gl = j >> 5, c = j & 31;
        T[gl * 168 + 64 + c] =
            (c < 22) ? hinS[(w * 16 + gl) * 168 + 128 + c] : (unsigned short)0;
    }

    short8 afA[5];
#pragma unroll
    for (int kt = 0; kt < 5; kt++)
        afA[kt] = *(const short8*)&hinS[(w * 16 + ln) * 168 + quad * 8 + kt * 32];
#pragma unroll
    for (int nt = 0; nt < 4; nt++) {
        floatx4 acc = (floatx4){0.f, 0.f, 0.f, 0.f};
        const unsigned short* bp = Whd + (nt * 16 + ln) * 160 + quad * 8;
#pragma unroll
        for (int kt = 0; kt < 5; kt++)
            acc = MF(afA[kt], *(const short8*)(bp + kt * 32), acc);
        float bias = LDWt<F32>(sb, nt * 16 + ln);
#pragma unroll
        for (int r = 0; r < 4; r++)
            T[(gq + r) * 168 + nt * 16 + ln] = f2us(fmaxf(acc[r] + bias, 0.f));
    }
    __syncthreads();

    short8 af20 = *(const short8*)&T[ln * 168 + quad * 8];
    short8 af21 = *(const short8*)&T[ln * 168 + quad * 8 + 32];

#pragma unroll
    for (int k = 0; k < 3; k++) {
        const unsigned short* Bw = Whd + 10240 + k * 4096;
        floatx4 acc[4];
#pragma unroll
        for (int nt = 0; nt < 4; nt++) {
            floatx4 a = (floatx4){0.f, 0.f, 0.f, 0.f};
            const unsigned short* bp = Bw + (nt * 16 + ln) * 64 + quad * 8;
            a = MF(af20, *(const short8*)bp, a);
            a = MF(af21, *(const short8*)(bp + 32), a);
            float b1 = LDWt<F32>(pb1, k * 64 + nt * 16 + ln);
#pragma unroll
            for (int r = 0; r < 4; r++) a[r] = fmaxf(a[r] + b1, 0.f);
            acc[nt] = a;
        }
#pragma unroll
        for (int o = 0; o < 3; o++) {
            float w2[4], part[4];
#pragma unroll
            for (int nt = 0; nt < 4; nt++)
                w2[nt] = LDWt<F32>(pW2, (size_t)k * 192 + (size_t)(nt * 16 + ln) * 3 + o);
#pragma unroll
            for (int r = 0; r < 4; r++)
                part[r] = acc[0][r] * w2[0] + acc[1][r] * w2[1] +
                          acc[2][r] * w2[2] + acc[3][r] * w2[3];
            quadred(part);
            if (ln == 0) {
                float b2 = LDWt<F32>(pb2, k * 3 + o);
#pragma unroll
                for (int r = 0; r < 4; r++)
                    STORE(k * 768 + (gw0 + gq + r) * 3 + o, part[r] + b2);
            }
        }
    }

    {
        const unsigned short* Bw = Whd + 22528;
        floatx4 acc[4];
#pragma unroll
        for (int nt = 0; nt < 4; nt++) {
            floatx4 a = (floatx4){0.f, 0.f, 0.f, 0.f};
            const unsigned short* bp = Bw + (nt * 16 + ln) * 64 + quad * 8;
            a = MF(af20, *(const short8*)bp, a);
            a = MF(af21, *(const short8*)(bp + 32), a);
            float b1 = LDWt<F32>(cb1, nt * 16 + ln);
#pragma unroll
            for (int r = 0; r < 4; r++) a[r] = fmaxf(a[r] + b1, 0.f);
            acc[nt] = a;
        }
#pragma unroll
        for (int o = 0; o < 5; o++) {
            float w2[4], part[4];
#pragma unroll
            for (int nt = 0; nt < 4; nt++)
                w2[nt] = LDWt<F32>(cW2, (size_t)(nt * 16 + ln) * 5 + o);
#pragma unroll
            for (int r = 0; r < 4; r++)
                part[r] = acc[0][r] * w2[0] + acc[1][r] * w2[1] +
                          acc[2][r] * w2[2] + acc[3][r] * w2[3];
            quadred(part);
            if (ln == 0) {
                float b2 = LDWt<F32>(cb2, o);
#pragma unroll
                for (int r = 0; r < 4; r++) {
                    float v = part[r] + b2;
                    T[(gq + r) * 168 + 86 + o] = f2us(v);
                    STORE(2304 + (gw0 + gq + r) * 5 + o, v);
                }
            }
        }
    }

#pragma unroll
    for (int k = 0; k < 2; k++) {
        const unsigned short* Bw = Whd + 26624 + k * 4096;
        floatx4 acc[4];
#pragma unroll
        for (int nt = 0; nt < 4; nt++) {
            floatx4 a = (floatx4){0.f, 0.f, 0.f, 0.f};
            const unsigned short* bp = Bw + (nt * 16 + ln) * 64 + quad * 8;
            a = MF(af20, *(const short8*)bp, a);
            a = MF(af21, *(const short8*)(bp + 32), a);
            float b1 = LDWt<F32>(fb1, k * 64 + nt * 16 + ln);
#pragma unroll
            for (int r = 0; r < 4; r++) a[r] = fmaxf(a[r] + b1, 0.f);
            acc[nt] = a;
        }
        float w2[4], part[4];
#pragma unroll
        for (int nt = 0; nt < 4; nt++)
            w2[nt] = LDWt<F32>(fW2, (size_t)k * 64 + nt * 16 + ln);
#pragma unroll
        for (int r = 0; r < 4; r++)
            part[r] = acc[0][r] * w2[0] + acc[1][r] * w2[1] +
                      acc[2][r] * w2[2] + acc[3][r] * w2[3];
        quadred(part);
        if (ln == 0) {
            float b2 = LDWt<F32>(fb2, k);
#pragma unroll
            for (int r = 0; r < 4; r++) {
                float v = part[r] + b2;
                T[(gq + r) * 168 + 91 + k] = f2us(v);
                STORE(3584 + k * 256 + (gw0 + gq + r), v);
            }
        }
    }
    __syncthreads();

    short8 af3 = *(const short8*)&T[ln * 168 + 64 + quad * 8];

    {
        const unsigned short* Bw = Whd + 34816;
        floatx4 acc[4];
#pragma unroll
        for (int nt = 0; nt < 4; nt++) {
            floatx4 a = (floatx4){0.f, 0.f, 0.f, 0.f};
            const unsigned short* bp = Bw + (nt * 16 + ln) * 96 + quad * 8;
            a = MF(af20, *(const short8*)bp, a);
            a = MF(af21, *(const short8*)(bp + 32), a);
            a = MF(af3, *(const short8*)(bp + 64), a);
            float b1 = LDWt<F32>(bb1, nt * 16 + ln);
#pragma unroll
            for (int r = 0; r < 4; r++) a[r] = fmaxf(a[r] + b1, 0.f);
            acc[nt] = a;
        }
        float w2[4], part[4];
#pragma unroll
        for (int nt = 0; nt < 4; nt++)
            w2[nt] = LDWt<F32>(bW2, nt * 16 + ln);
#pragma unroll
        for (int r = 0; r < 4; r++)
            part[r] = acc[0][r] * w2[0] + acc[1][r] * w2[1] +
                      acc[2][r] * w2[2] + acc[3][r] * w2[3];
        quadred(part);
        if (ln == 0) {
            float b2 = LDWt<F32>(bb2, 0);
#pragma unroll
            for (int r = 0; r < 4; r++) {
                float v = part[r] + b2;
                T[(gq + r) * 168 + 93] = f2us(v);
                STORE(4096 + (gw0 + gq + r), v);
            }
        }
    }
    __syncthreads();

    af3 = *(const short8*)&T[ln * 168 + 64 + quad * 8];

    {
        const unsigned short* Bw = Whd + 40960;
        floatx4 acc[4];
#pragma unroll
        for (int nt = 0; nt < 4; nt++) {
            floatx4 a = (floatx4){0.f, 0.f, 0.f, 0.f};
            const unsigned short* bp = Bw + (nt * 16 + ln) * 96 + quad * 8;
            a = MF(af20, *(const short8*)bp, a);
            a = MF(af21, *(const short8*)(bp + 32), a);
            a = MF(af3, *(const short8*)(bp + 64), a);
            float b1 = LDWt<F32>(zb1, nt * 16 + ln);
#pragma unroll
            for (int r = 0; r < 4; r++) a[r] = fmaxf(a[r] + b1, 0.f);
            acc[nt] = a;
        }
#pragma unroll
        for (int o = 0; o < 8; o++) {
            float w2[4], part[4];
#pragma unroll
            for (int nt = 0; nt < 4; nt++)
                w2[nt] = LDWt<F32>(zW2, (size_t)(nt * 16 + ln) * 8 + o);
#pragma unroll
            for (int r = 0; r < 4; r++)
                part[r] = acc[0][r] * w2[0] + acc[1][r] * w2[1] +
                          acc[2][r] * w2[2] + acc[3][r] * w2[3];
            quadred(part);
            if (ln == 0) {
                float b2 = LDWt<F32>(zb2, o);
#pragma unroll
                for (int r = 0; r < 4; r++)
                    STORE(4352 + (gw0 + gq + r) * 8 + o, part[r] + b2);
            }
        }
    }
#undef STORE
}

__global__ __launch_bounds__(256) void k_heads_mfma(
    const unsigned* __restrict__ hroot32, const void* __restrict__ x,
    const int* __restrict__ node0, const unsigned short* __restrict__ Whd,
    const void* sb, const void* pb1, const void* pW2, const void* pb2,
    const void* cb1, const void* cW2, const void* cb2,
    const void* fb1, const void* fW2, const void* fb2,
    const void* bb1, const void* bW2, const void* bb2,
    const void* zb1, const void* zW2, const void* zb2,
    void* __restrict__ outv, const int* __restrict__ flagd) {
    if (*flagd)
        heads_mfma_body<1>(hroot32, x, node0, Whd, sb, pb1, pW2, pb2, cb1, cW2, cb2,
                           fb1, fW2, fb2, bb1, bW2, bb2, zb1, zW2, zb2, outv);
    else
        heads_mfma_body<0>(hroot32, x, node0, Whd, sb, pb1, pW2, pb2, cb1, cW2, cb2,
                           fb1, fW2, fb2, bb1, bW2, bb2, zb1, zW2, zb2, outv);
}

// ---------------- host ----------------

extern "C" void kernel_launch(void* const* d_in, const int* in_sizes, int n_in,
                              void* d_out, int out_size, void* d_ws, size_t ws_size,
                              hipStream_t stream) {
    const void* x     = d_in[0];
    const int*  ei    = (const int*)d_in[1];
    const int*  batch = (const int*)d_in[2];

    int N = in_sizes[0] / 128;
    int E = in_sizes[1] / 2;

    char* w = (char*)d_ws;
    float4* asad = (float4*)w;              w += (size_t)N * 16;
    unsigned short* A = (unsigned short*)w; w += (size_t)N * 128 * 2;
    unsigned short* B = (unsigned short*)w; w += (size_t)N * 128 * 2;
    unsigned short* Wt = (unsigned short*)w; w += 3 * 16384 * 2;
    unsigned short* Whd = (unsigned short*)w; w += 47104 * 2;
    float* asF = (float*)w;                 w += 384 * 4;
    float* adF = (float*)w;                 w += 384 * 4;
    float* bF = (float*)w;                  w += 384 * 4;
    int* wl1 = (int*)w;                     w += (size_t)N * 4;
    int* wl2 = (int*)w;                     w += (size_t)N * 4;
    int* adj = (int*)w;                     w += (size_t)N * ADJ_SLOTS * 4;
    int* ovfD = (int*)w;                    w += (size_t)E * 4;
    int* ovfS = (int*)w;                    w += (size_t)E * 4;
    int* node0 = (int*)w;                   w += 256 * 4;
    unsigned* hroot = (unsigned*)w;         w += 256 * 128 * 2;
    // ---- contiguous zero-region (zeroed by k_detect_zero) ----
    char* zbase = w;
    int* cur = (int*)w;                     w += (size_t)N * 4;
    unsigned char* flag1 = (unsigned char*)w; w += (size_t)N;
    int* nact = (int*)w;                    w += 64 * 4;  // [0]=|wl1|, [32]=|wl2|
    int* ovfCnt = (int*)w;                  w += 64;
    size_t zbytes = (size_t)N * 5 + 64 * 4 + 64;
    // ---- densely-written / written-once (no zeroing needed) ----
    int* flagd = (int*)w;                   w += 64;
    unsigned char* rootb = (unsigned char*)w; w += (size_t)N;
    unsigned char* flag2 = (unsigned char*)w; w += (size_t)N;

    int nb = (N + 255) / 256;
    int nvec = N * 16;
    int nbx8 = (nvec + 255) / 256;
    int nbE = (E + 255) / 256;
    int zBlocks = (int)((zbytes + 4095) / 4096);

    // K1: dtype probe -> flagd, zero {cur,flag1,nact,ovfCnt}, node0/rootb/flag2
    k_detect_zero<<<1 + zBlocks + nb, 256, 0, stream>>>(
        x, flagd, zbase, zbytes, batch, node0, rootb, flag2, N, zBlocks);

    // K2: mark2 edge scan + weight transposes + x-convert (direct-indexed)
    k_prep<<<nbE + 194 + 184 + nbx8, 256, 0, stream>>>(
        x, A, nvec, d_in[3], Wt, d_in[4], d_in[5], d_in[6],
        asF, adF, bF,
        d_in[7], d_in[9], d_in[13], d_in[17], d_in[21], d_in[25], Whd,
        ei, rootb, flag2, E, flagd, nbE);

    // K3: layer-0 GEMM (grid-stride tiles, LDS-staged Wt) + mark1
    k_gemm0_mark<<<nbE + nb + 800, 256, 0, stream>>>(
        A, x, Wt, B, asad, asF, adF, N, ei, flag2, flag1, E, nbE, nb, flagd);

    // K4: cursor scatter into 128-slot adj (+overflow) + atomic-append worklists
    k_scatter_wl<<<nbE + nb, 256, 0, stream>>>(
        ei, cur, flag1, flag2, adj, ovfD, ovfS, ovfCnt, wl1, wl2, nact, E, N, nbE);

    // K5: layer-0 agg over wl1 (grid-stride waves)
    k_gat_agg<<<2048, 256, 0, stream>>>(
        (const uint2*)B, asad, cur, adj, ovfD, ovfS, ovfCnt, bF, (uint2*)A,
        nact, 0, 1, 0, wl1);

    // K6: layer-1 gather-GEMM over wl1
    k_gemm_mfma<<<512, 256, 0, stream>>>(
        A, Wt + 16384, B, asad, asF + 128, adF + 128, N, wl1, nact);

    // K7: layer-1 agg over wl2
    k_gat_agg<<<512, 256, 0, stream>>>(
        (const uint2*)B, asad, cur, adj, ovfD, ovfS, ovfCnt, bF + 128, (uint2*)A,
        nact + 32, 0, 1, 0, wl2);

    // K8: layer-2 gather-GEMM over wl2
    k_gemm_mfma<<<128, 256, 0, stream>>>(
        A, Wt + 2 * 16384, B, asad, asF + 256, adF + 256, N, wl2, nact + 32);

    // K9: root aggregation (256 roots, 32 blocks — R11 lesson: keep this as a
    // separate well-parallelized launch, not fused into 4-block heads)
    k_gat_agg<<<32, 256, 0, stream>>>(
        (const uint2*)B, asad, cur, adj, ovfD, ovfS, ovfCnt, bF + 256, (uint2*)hroot,
        nact, 256, 0, 1, node0);

    // K10: MFMA-batched heads
    k_heads_mfma<<<4, 256, 0, stream>>>(
        hroot, x, node0, Whd,
        d_in[8], d_in[10], d_in[11], d_in[12],
        d_in[14], d_in[15], d_in[16],
        d_in[18], d_in[19], d_in[20],
        d_in[22], d_in[23], d_in[24],
        d_in[26], d_in[27], d_in[28],
        d_out, flagd);
}